// Round 15
// baseline (208.879 us; speedup 1.0000x reference)
//
#include <hip/hip_runtime.h>
#include <hip/hip_bf16.h>

#define N_NODES 8192
#define M_NEI   32
#define K_PTS   8
#define D       64
#define EPS_    1e-7f

typedef float f4v __attribute__((ext_vector_type(4)));
typedef short s8v __attribute__((ext_vector_type(8)));

__device__ __forceinline__ ushort f2bf(float f) {
  __hip_bfloat16 h = __float2bfloat16(f);
  return *reinterpret_cast<ushort*>(&h);
}
__device__ __forceinline__ float bf2f(ushort u) {
  __hip_bfloat16 h;
  *reinterpret_cast<ushort*>(&h) = u;
  return __bfloat162float(h);
}
__device__ __forceinline__ float frcp(float x)  { return __builtin_amdgcn_rcpf(x); }
__device__ __forceinline__ float frsq(float x)  { return __builtin_amdgcn_rsqf(x); }
__device__ __forceinline__ float fsqrt(float x) { return __builtin_amdgcn_sqrtf(x); }
__device__ __forceinline__ float facosh(float a) {
  float den = fsqrt(fmaxf(a * a - 1.f, 1e-14f));
  return __logf(a + den);
}

// ---- DPP / swizzle cross-lane ----
template<int CTRL>
__device__ __forceinline__ float dppadd(float v) {
  int t = __builtin_amdgcn_update_dpp(0, __float_as_int(v), CTRL, 0xf, 0xf, true);
  return v + __int_as_float(t);
}
template<int CTRL>
__device__ __forceinline__ float dppmov(float v) {
  return __int_as_float(__builtin_amdgcn_update_dpp(0, __float_as_int(v), CTRL, 0xf, 0xf, true));
}
__device__ __forceinline__ float swz_xor4(float v) {   // lane ^= 4
  return __int_as_float(__builtin_amdgcn_ds_swizzle(__float_as_int(v), 0x101F));
}
__device__ __forceinline__ float sum8(float v) {
  v = dppadd<0xB1>(v);    // quad_perm xor1
  v = dppadd<0x4E>(v);    // quad_perm xor2
  v = dppadd<0x141>(v);   // row_half_mirror
  return v;
}
__device__ __forceinline__ float sum16(float v) {
  v = dppadd<0x121>(v);   // row_ror:1
  v = dppadd<0x122>(v);   // row_ror:2
  v = dppadd<0x124>(v);   // row_ror:4
  v = dppadd<0x128>(v);   // row_ror:8
  return v;
}

// epilogue helpers — f4v BY VALUE (rule #20: no pointers into register arrays)
__device__ __forceinline__ void store_row(float* rw, int cl, f4v y) {
  rw[cl]      = y[0];
  rw[16 + cl] = y[1];
  rw[32 + cl] = y[2];
  rw[48 + cl] = y[3];
}
__device__ __forceinline__ void norm_add(const float* rw, int cl, f4v y, f4v& s) {
  float v0 = y[0] + rw[cl];
  float v1 = y[1] + rw[16 + cl];
  float v2 = y[2] + rw[32 + cl];
  float v3 = y[3] + rw[48 + cl];
  float ip = v0*v0 + v1*v1 + v2*v2 + v3*v3;
  if (cl == 0) ip -= 2.f * v0 * v0;
  ip = sum16(ip);                               // per-m l_inner
  float rin = frsq(fmaxf(fabsf(ip), 1e-8f));
  s[0] += v0 * rin; s[1] += v1 * rin;
  s[2] += v2 * rin; s[3] += v3 * rin;
}

// ---------------- prep: x_kernel rows (K x 64) + exp(scale) tail ----------------
__global__ void prep_xk(const float* __restrict__ kp, const float* __restrict__ scale,
                        float* __restrict__ xk) {
  int d = threadIdx.x;  // 64 threads
  for (int kk = 0; kk < K_PTS - 1; ++kk) {
    float v = kp[(kk + 1) * D + d];
    float p = (d == 0) ? 0.f : v * v;
    #pragma unroll
    for (int s = 1; s < 64; s <<= 1) p += __shfl_xor(p, s);
    float un = sqrtf(fmaxf(p, 1e-14f));
    float sh = sinhf(un) / un;
    xk[kk * D + d] = (d == 0) ? coshf(un) : sh * v;
  }
  xk[(K_PTS - 1) * D + d] = (d == 0) ? 1.f : 0.f;
  if (d < K_PTS) xk[K_PTS * D + d] = expf(scale[d]);
}

// ---------------- prep: W -> bf16 hi/lo MFMA B-fragments ----------------
__global__ void prep_wb(const float* __restrict__ W, ushort* __restrict__ WF) {
  int idx = blockIdx.x * 256 + threadIdx.x;   // 4096 total
  int k    = idx >> 9;
  int ct   = (idx >> 7) & 3;
  int ks   = (idx >> 6) & 1;
  int lane = idx & 63;
  int o  = ct * 16 + (lane & 15);
  int db = (lane >> 4) * 8 + ks * 32;
  const float* wrow = W + (k * 64 + o) * 64 + db;   // d-contiguous
  s8v hi, lo;
  #pragma unroll
  for (int j = 0; j < 8; ++j) {
    float w = wrow[j];
    ushort h = f2bf(w);
    hi[j] = (short)h;
    lo[j] = (short)f2bf(w - bf2f(h));
  }
  int f = (k * 4 + ct) * 2 + ks;
  *(s8v*)(WF + (size_t)(f * 2 + 0) * 512 + lane * 8) = hi;
  *(s8v*)(WF + (size_t)(f * 2 + 1) * 512 + lane * 8) = lo;
}

// ---- main: 256 threads = 4 waves; wave = (wm = m-half, wk = k-half) ----
// (256,5): per-kq folding -> live set ~80 regs (acc[4]=16 only, dies each kq).
// Tripwire: WRITE_SIZE >> 2 MB means spill — revert to (256,4) config next.
__launch_bounds__(256, 5)
__global__ void kpa_main(const float* __restrict__ x, const int* __restrict__ nei,
                         const int* __restrict__ mask, const ushort* __restrict__ WF,
                         const float* __restrict__ b, const float* __restrict__ scale,
                         const float* __restrict__ xk, float* __restrict__ out) {
  __shared__ __align__(16) float  xk_s[K_PTS * D + 8];   // + exp(scale) tail
  __shared__ __align__(16) ushort Ah_lds[M_NEI * D];     // bf16 hi, XOR-swizzled
  __shared__ __align__(16) ushort Al_lds[M_NEI * D];     // bf16 lo
  __shared__ float dis_s[K_PTS * 33];
  __shared__ __align__(8)  float  hss[K_PTS * M_NEI * 2];   // (h0,ss)->(dmsq,dmtime)
  __shared__ __align__(16) float  red_e[2][2][8 * 68];   // [reader_wk][wm] foreign-r yacc
  __shared__ __align__(16) float  redp3[4][64];          // per-wave mean partials

  const int n  = blockIdx.x;
  const int t  = threadIdx.x;
  const int w4 = t >> 6;     // wave 0..3
  const int l  = t & 63;
  const int cl = l & 15;     // MFMA col index
  const int gr = l >> 4;     // MFMA k-group / row-subgroup
  const int wm = w4 & 1;     // m-half (rows wm*16..+16)
  const int wk = w4 >> 1;    // k-quad (k = wk*4..+4)

  // stage xk (+es tail); consumed only after barrier #1
  xk_s[t] = xk[t]; xk_s[t + 256] = xk[t + 256];
  if (t < 8) xk_s[512 + t] = xk[512 + t];

  // ---- prologue: 8 lanes per neighbor; m = t>>3, l8 = t&7 owns d in [l8*8,+8)
  const int mP  = t >> 3;
  const int l8  = t & 7;
  float x0v[8];
  {
    const int d0 = l8 * 8;
    const int ni = nei[n * M_NEI + mP];
    float y[8], xr[8];
    float y0 = x[ni * D];                 // d=0 elem, L1-hit
    {
      float4 ya = *(const float4*)(x + ni * D + d0);
      float4 yb = *(const float4*)(x + ni * D + d0 + 4);
      y[0]=ya.x; y[1]=ya.y; y[2]=ya.z; y[3]=ya.w;
      y[4]=yb.x; y[5]=yb.y; y[6]=yb.z; y[7]=yb.w;
      float4 ra = *(const float4*)(x + n * D + d0);   // xr direct (L1/L2)
      float4 rb = *(const float4*)(x + n * D + d0 + 4);
      xr[0]=ra.x; xr[1]=ra.y; xr[2]=ra.z; xr[3]=ra.w;
      xr[4]=rb.x; xr[5]=rb.y; xr[6]=rb.z; xr[7]=rb.w;
    }
    const float xr0 = x[n * D];           // uniform -> s_load
    float p = 0.f;
    #pragma unroll
    for (int j = 0; j < 8; ++j) p += xr[j] * y[j];
    if (l8 == 0) p -= 2.f * xr[0] * y[0];
    p = sum8(p);
    float alpha = fmaxf(-p, 1.f + EPS_);
    float den = fsqrt(fmaxf(alpha * alpha - 1.f, 1e-14f));
    float dd  = __logf(alpha + den);          // acosh(alpha)
    float f   = dd * frcp(den);
    float v[8];
    #pragma unroll
    for (int j = 0; j < 8; ++j) v[j] = f * (y[j] - alpha * xr[j]);
    float v0 = f * (y0 - alpha * xr0);        // recomputed locally, no shfl
    float c  = -v0 * frcp(1.f + xr0);
    float wv[8];
    float q = 0.f;
    #pragma unroll
    for (int j = 0; j < 8; ++j) { wv[j] = v[j] + c * xr[j]; q += wv[j] * wv[j]; }
    if (l8 == 0) q -= wv[0] * wv[0];
    q = sum8(q);
    float un = fsqrt(fmaxf(q, 1e-14f));
    float e  = __expf(un);
    float ei = frcp(e);
    float sh = (0.5f * (e - ei)) * frcp(un);  // sinh(un)/un
    #pragma unroll
    for (int j = 0; j < 8; ++j) x0v[j] = sh * wv[j];
    if (l8 == 0) x0v[0] = 0.5f * (e + ei);    // cosh(un)
    // A-tile: bf16 hi/lo via truncation split, XOR-swizzled
    {
      s8v hi, lo;
      #pragma unroll
      for (int j = 0; j < 8; ++j) {
        uint u = __float_as_uint(x0v[j]);
        hi[j] = (short)(ushort)(u >> 16);
        float lof = x0v[j] - __uint_as_float(u & 0xffff0000u);
        uint ul = __float_as_uint(lof);
        lo[j] = (short)(ushort)((ul + 0x7fffu + ((ul >> 16) & 1u)) >> 16);
      }
      int byte = mP * 128 + d0 * 2;
      int swz  = byte ^ ((mP & 7) << 4);
      *(s8v*)((char*)Ah_lds + swz) = hi;
      *(s8v*)((char*)Al_lds + swz) = lo;
    }
  }
  __syncthreads();   // #1: xk_s ready, A-tiles ready

  // ---- dis: 8 partial dots, 3-stage reduce-scatter -> lane l8 holds kk==l8
  {
    const int d0 = l8 * 8;
    float msk = (float)mask[n * M_NEI + mP];
    if (l8 == 0) x0v[0] = -x0v[0];            // Lorentzian sign for d=0 term
    float pk[8];
    #pragma unroll
    for (int kk = 0; kk < K_PTS; ++kk) {
      const float* xkp = xk_s + kk * D + d0;
      float pp = 0.f;
      #pragma unroll
      for (int j = 0; j < 8; ++j) pp += x0v[j] * xkp[j];
      pk[kk] = pp;
    }
    const bool hi4 = (l8 & 4);
    float s1[4];
    #pragma unroll
    for (int j = 0; j < 4; ++j) {
      float give = hi4 ? pk[j] : pk[j + 4];
      float keep = hi4 ? pk[j + 4] : pk[j];
      s1[j] = keep + swz_xor4(give);
    }
    const bool hi2 = (l8 & 2);
    float s2[2];
    #pragma unroll
    for (int j = 0; j < 2; ++j) {
      float give = hi2 ? s1[j] : s1[j + 2];
      float keep = hi2 ? s1[j + 2] : s1[j];
      s2[j] = keep + dppmov<0x4E>(give);
    }
    const bool hi1 = (l8 & 1);
    float give = hi1 ? s2[0] : s2[1];
    float keep = hi1 ? s2[1] : s2[0];
    float mypp = keep + dppmov<0xB1>(give);
    float al_ = fmaxf(-mypp, 1.f + EPS_);
    dis_s[l8 * 33 + mP] = facosh(al_) * msk;
  }
  __syncthreads();   // #2: dis_s ready (cross-wave)

  // ---- MFMA: A-frags once (rows wm*16+cl); per-kq fold (acc dies each kq)
  const int row = wm * 16 + cl;
  s8v ah[2], alo[2];
  #pragma unroll
  for (int ks = 0; ks < 2; ++ks) {
    int byte = row * 128 + (gr * 8 + ks * 32) * 2;
    int swz  = byte ^ ((row & 7) << 4);
    ah[ks]  = *(const s8v*)((const char*)Ah_lds + swz);
    alo[ks] = *(const s8v*)((const char*)Al_lds + swz);
  }

  f4v yacc[4];   // [r] over ct — compile-time indices only
  #pragma unroll
  for (int r = 0; r < 4; ++r) yacc[r] = (f4v){0.f, 0.f, 0.f, 0.f};

  #pragma unroll
  for (int kq = 0; kq < 4; ++kq) {
    const int k = wk * 4 + kq;
    f4v acc[4];   // ONE kq retained -> 16 regs
    #pragma unroll
    for (int ct = 0; ct < 4; ++ct) {
      float bv = b[k * 64 + ct * 16 + cl];
      f4v a = (f4v){bv, bv, bv, bv};           // bias folded into C-init
      #pragma unroll
      for (int ks = 0; ks < 2; ++ks) {
        int fi = (k * 4 + ct) * 2 + ks;
        s8v bh = *(const s8v*)(WF + (size_t)(fi * 2 + 0) * 512 + l * 8);
        s8v bl = *(const s8v*)(WF + (size_t)(fi * 2 + 1) * 512 + l * 8);
        a = __builtin_amdgcn_mfma_f32_16x16x32_bf16(ah[ks],  bh, a, 0, 0, 0);
        a = __builtin_amdgcn_mfma_f32_16x16x32_bf16(ah[ks],  bl, a, 0, 0, 0);
        a = __builtin_amdgcn_mfma_f32_16x16x32_bf16(alo[ks], bh, a, 0, 0, 0);
      }
      acc[ct] = a;
    }
    // pass A: ss per (k,m); cl==0 lane stores (h0, ss)  [wave-local pairs]
    #pragma unroll
    for (int r = 0; r < 4; ++r) {
      float ss = acc[0][r]*acc[0][r] + acc[1][r]*acc[1][r]
               + acc[2][r]*acc[2][r] + acc[3][r]*acc[3][r];
      ss = sum16(ss);
      if (cl == 0) {
        const int m = wm * 16 + gr * 4 + r;
        *(float2*)&hss[(k * M_NEI + m) * 2] = make_float2(acc[0][r], ss);
      }
    }
    // mini pass B: WAVE-LOCAL — this k's 16 m on lanes 0-15; es wave-uniform
    {
      const float es = xk_s[512 + k];
      if (l < 16) {
        const int mB = wm * 16 + l;
        float2 hp = *(const float2*)&hss[(k * M_NEI + mB) * 2];
        float h0 = hp.x, ss = hp.y;
        float nar2 = fmaxf(ss - h0 * h0, 1e-8f);
        float time = es * frcp(1.f + __expf(-h0)) + 1.0001f;
        float sq   = fsqrt(time * time - 1.f) * frsq(nar2);
        float dm   = dis_s[k * 33 + mB];
        *(float2*)&hss[(k * M_NEI + mB) * 2] = make_float2(dm * sq, dm * time);
      }
    }
    // pass C: FMA accumulation against broadcast (dmsq, dmtime) [wave-local]
    #pragma unroll
    for (int r = 0; r < 4; ++r) {
      const int m = wm * 16 + gr * 4 + r;
      float2 dd = *(const float2*)&hss[(k * M_NEI + m) * 2];  // broadcast read
      yacc[r][0] += (cl == 0) ? dd.y : dd.x * acc[0][r];
      yacc[r][1] += dd.x * acc[1][r];
      yacc[r][2] += dd.x * acc[2][r];
      yacc[r][3] += dd.x * acc[3][r];
    }
  }

  // ---- balanced cross-wk combine; wave-uniform branch, LITERAL yacc indices
  if (wk == 0) {
    store_row(&red_e[1][wm][(gr * 2 + 0) * 68], cl, yacc[2]);
    store_row(&red_e[1][wm][(gr * 2 + 1) * 68], cl, yacc[3]);
  } else {
    store_row(&red_e[0][wm][(gr * 2 + 0) * 68], cl, yacc[0]);
    store_row(&red_e[0][wm][(gr * 2 + 1) * 68], cl, yacc[1]);
  }
  __syncthreads();   // #3

  {
    f4v s = (f4v){0.f, 0.f, 0.f, 0.f};
    if (wk == 0) {
      norm_add(&red_e[0][wm][(gr * 2 + 0) * 68], cl, yacc[0], s);
      norm_add(&red_e[0][wm][(gr * 2 + 1) * 68], cl, yacc[1], s);
    } else {
      norm_add(&red_e[1][wm][(gr * 2 + 0) * 68], cl, yacc[2], s);
      norm_add(&red_e[1][wm][(gr * 2 + 1) * 68], cl, yacc[3], s);
    }
    // sum across gr rows (this wave's 8 m)
    #pragma unroll
    for (int j2 = 0; j2 < 4; ++j2) {
      float z = s[j2];
      z += __shfl_xor(z, 16); z += __shfl_xor(z, 32);
      s[j2] = z;
    }
    if (gr == 0) {
      #pragma unroll
      for (int j2 = 0; j2 < 4; ++j2) redp3[w4][j2 * 16 + cl] = s[j2];
    }
  }
  __syncthreads();   // #4

  if (t < 64) {
    float mv = (redp3[0][t] + redp3[1][t] + redp3[2][t] + redp3[3][t]) * (1.f / 32.f);
    float ip = (t == 0) ? -mv * mv : mv * mv;
    ip = sum16(ip);
    ip += __shfl_xor(ip, 16); ip += __shfl_xor(ip, 32);
    out[n * D + t] = mv * frsq(fmaxf(fabsf(ip), 1e-8f));
  }
}

extern "C" void kernel_launch(void* const* d_in, const int* in_sizes, int n_in,
                              void* d_out, int out_size, void* d_ws, size_t ws_size,
                              hipStream_t stream) {
  const float* x     = (const float*)d_in[0];
  const int*   nei   = (const int*)d_in[1];
  const int*   mask  = (const int*)d_in[2];
  const float* W     = (const float*)d_in[3];
  const float* b     = (const float*)d_in[4];
  const float* scale = (const float*)d_in[5];
  const float* kp    = (const float*)d_in[6];
  float* out = (float*)d_out;

  ushort* WF = (ushort*)d_ws;               // 64 frags x 2 parts x 512 ushort = 128 KiB
  float*  xk = (float*)(WF + 65536);        // 8*64 + 8 floats

  prep_wb<<<16, 256, 0, stream>>>(W, WF);
  prep_xk<<<1, 64, 0, stream>>>(kp, scale, xk);
  kpa_main<<<N_NODES, 256, 0, stream>>>(x, nei, mask, WF, b, scale, xk, out);
}

// Round 16
// 102.987 us; speedup vs baseline: 2.0282x; 2.0282x over previous
//
#include <hip/hip_runtime.h>
#include <hip/hip_bf16.h>

#define N_NODES 8192
#define M_NEI   32
#define K_PTS   8
#define D       64
#define EPS_    1e-7f

typedef float f4v __attribute__((ext_vector_type(4)));
typedef short s8v __attribute__((ext_vector_type(8)));

__device__ __forceinline__ ushort f2bf(float f) {
  __hip_bfloat16 h = __float2bfloat16(f);
  return *reinterpret_cast<ushort*>(&h);
}
__device__ __forceinline__ float bf2f(ushort u) {
  __hip_bfloat16 h;
  *reinterpret_cast<ushort*>(&h) = u;
  return __bfloat162float(h);
}
__device__ __forceinline__ float frcp(float x)  { return __builtin_amdgcn_rcpf(x); }
__device__ __forceinline__ float frsq(float x)  { return __builtin_amdgcn_rsqf(x); }
__device__ __forceinline__ float fsqrt(float x) { return __builtin_amdgcn_sqrtf(x); }
__device__ __forceinline__ float facosh(float a) {
  float den = fsqrt(fmaxf(a * a - 1.f, 1e-14f));
  return __logf(a + den);
}

// ---- DPP / swizzle cross-lane ----
template<int CTRL>
__device__ __forceinline__ float dppadd(float v) {
  int t = __builtin_amdgcn_update_dpp(0, __float_as_int(v), CTRL, 0xf, 0xf, true);
  return v + __int_as_float(t);
}
template<int CTRL>
__device__ __forceinline__ float dppmov(float v) {
  return __int_as_float(__builtin_amdgcn_update_dpp(0, __float_as_int(v), CTRL, 0xf, 0xf, true));
}
__device__ __forceinline__ float swz_xor4(float v) {   // lane ^= 4
  return __int_as_float(__builtin_amdgcn_ds_swizzle(__float_as_int(v), 0x101F));
}
__device__ __forceinline__ float sum8(float v) {
  v = dppadd<0xB1>(v);    // quad_perm xor1
  v = dppadd<0x4E>(v);    // quad_perm xor2
  v = dppadd<0x141>(v);   // row_half_mirror
  return v;
}
__device__ __forceinline__ float sum16(float v) {
  v = dppadd<0x121>(v);   // row_ror:1
  v = dppadd<0x122>(v);   // row_ror:2
  v = dppadd<0x124>(v);   // row_ror:4
  v = dppadd<0x128>(v);   // row_ror:8
  return v;
}

// ---------------- prep: x_kernel rows (K x 64) + exp(scale) tail ----------------
__global__ void prep_xk(const float* __restrict__ kp, const float* __restrict__ scale,
                        float* __restrict__ xk) {
  int d = threadIdx.x;  // 64 threads
  for (int kk = 0; kk < K_PTS - 1; ++kk) {
    float v = kp[(kk + 1) * D + d];
    float p = (d == 0) ? 0.f : v * v;
    #pragma unroll
    for (int s = 1; s < 64; s <<= 1) p += __shfl_xor(p, s);
    float un = sqrtf(fmaxf(p, 1e-14f));
    float sh = sinhf(un) / un;
    xk[kk * D + d] = (d == 0) ? coshf(un) : sh * v;
  }
  xk[(K_PTS - 1) * D + d] = (d == 0) ? 1.f : 0.f;
  if (d < K_PTS) xk[K_PTS * D + d] = expf(scale[d]);
}

// ---------------- prep: W -> bf16 hi/lo MFMA B-fragments ----------------
__global__ void prep_wb(const float* __restrict__ W, ushort* __restrict__ WF) {
  int idx = blockIdx.x * 256 + threadIdx.x;   // 4096 total
  int k    = idx >> 9;
  int ct   = (idx >> 7) & 3;
  int ks   = (idx >> 6) & 1;
  int lane = idx & 63;
  int o  = ct * 16 + (lane & 15);
  int db = (lane >> 4) * 8 + ks * 32;
  const float* wrow = W + (k * 64 + o) * 64 + db;   // d-contiguous
  s8v hi, lo;
  #pragma unroll
  for (int j = 0; j < 8; ++j) {
    float w = wrow[j];
    ushort h = f2bf(w);
    hi[j] = (short)h;
    lo[j] = (short)f2bf(w - bf2f(h));
  }
  int f = (k * 4 + ct) * 2 + ks;
  *(s8v*)(WF + (size_t)(f * 2 + 0) * 512 + lane * 8) = hi;
  *(s8v*)(WF + (size_t)(f * 2 + 1) * 512 + lane * 8) = lo;
}

// ---- main: 256 threads = 4 waves; wave = (wm = m-half, wk = k-half) ----
// (256,4): 128-reg cap — acc[4][4] retention fits, NO scratch spill.
// Proven config (round 11: 103.2 us). (256,5)/(256,6) all spill (r10/r14/r15).
__launch_bounds__(256, 4)
__global__ void kpa_main(const float* __restrict__ x, const int* __restrict__ nei,
                         const int* __restrict__ mask, const ushort* __restrict__ WF,
                         const float* __restrict__ b, const float* __restrict__ scale,
                         const float* __restrict__ xk, float* __restrict__ out) {
  __shared__ __align__(16) float  xr_s[D];
  __shared__ __align__(16) float  xk_s[K_PTS * D];
  __shared__ __align__(16) ushort Ah_lds[M_NEI * D];     // bf16 hi, XOR-swizzled
  __shared__ __align__(16) ushort Al_lds[M_NEI * D];     // bf16 lo
  __shared__ float dis_s[K_PTS * 33];
  __shared__ __align__(8)  float  hss[K_PTS * M_NEI * 2];   // (h0,ss)->(dmsq,dmtime) in place
  __shared__ __align__(16) float  red_h[2][16 * 68];     // per-wm half: wk=1's yacc
  __shared__ __align__(16) float  redp2[2][64];          // per-wm mean partials

  const int n  = blockIdx.x;
  const int t  = threadIdx.x;
  const int w4 = t >> 6;     // wave 0..3
  const int l  = t & 63;
  const int cl = l & 15;     // MFMA col index
  const int gr = l >> 4;     // MFMA k-group / row-subgroup
  const int wm = w4 & 1;     // m-half (rows wm*16..+16)
  const int wk = w4 >> 1;    // k-quad (k = wk*4..+4)

  if (t < D) xr_s[t] = x[n * D + t];
  xk_s[t] = xk[t]; xk_s[t + 256] = xk[t + 256];
  __syncthreads();

  // ---- prologue: 8 lanes per neighbor; m = t>>3, l8 = t&7 owns d in [l8*8,+8)
  {
    const int m  = t >> 3;
    const int l8 = t & 7;
    const int d0 = l8 * 8;
    const int ni = nei[n * M_NEI + m];
    float y[8], xr[8];
    float y0 = x[ni * D];                 // d=0 elem, L1-hit
    {
      float4 ya = *(const float4*)(x + ni * D + d0);
      float4 yb = *(const float4*)(x + ni * D + d0 + 4);
      y[0]=ya.x; y[1]=ya.y; y[2]=ya.z; y[3]=ya.w;
      y[4]=yb.x; y[5]=yb.y; y[6]=yb.z; y[7]=yb.w;
      float4 ra = *(const float4*)(xr_s + d0);
      float4 rb = *(const float4*)(xr_s + d0 + 4);
      xr[0]=ra.x; xr[1]=ra.y; xr[2]=ra.z; xr[3]=ra.w;
      xr[4]=rb.x; xr[5]=rb.y; xr[6]=rb.z; xr[7]=rb.w;
    }
    const float xr0 = xr_s[0];
    float p = 0.f;
    #pragma unroll
    for (int j = 0; j < 8; ++j) p += xr[j] * y[j];
    if (l8 == 0) p -= 2.f * xr[0] * y[0];
    p = sum8(p);
    float alpha = fmaxf(-p, 1.f + EPS_);
    float den = fsqrt(fmaxf(alpha * alpha - 1.f, 1e-14f));
    float dd  = __logf(alpha + den);          // acosh(alpha)
    float f   = dd * frcp(den);
    float v[8];
    #pragma unroll
    for (int j = 0; j < 8; ++j) v[j] = f * (y[j] - alpha * xr[j]);
    float v0 = f * (y0 - alpha * xr0);        // recomputed locally, no shfl
    float c  = -v0 * frcp(1.f + xr0);
    float wv[8];
    float q = 0.f;
    #pragma unroll
    for (int j = 0; j < 8; ++j) { wv[j] = v[j] + c * xr[j]; q += wv[j] * wv[j]; }
    if (l8 == 0) q -= wv[0] * wv[0];
    q = sum8(q);
    float un = fsqrt(fmaxf(q, 1e-14f));
    float e  = __expf(un);
    float ei = frcp(e);
    float sh = (0.5f * (e - ei)) * frcp(un);  // sinh(un)/un
    float x0v[8];
    #pragma unroll
    for (int j = 0; j < 8; ++j) x0v[j] = sh * wv[j];
    if (l8 == 0) x0v[0] = 0.5f * (e + ei);    // cosh(un)
    // A-tile: bf16 hi/lo via truncation split, XOR-swizzled
    {
      s8v hi, lo;
      #pragma unroll
      for (int j = 0; j < 8; ++j) {
        uint u = __float_as_uint(x0v[j]);
        hi[j] = (short)(ushort)(u >> 16);
        float lof = x0v[j] - __uint_as_float(u & 0xffff0000u);
        uint ul = __float_as_uint(lof);
        lo[j] = (short)(ushort)((ul + 0x7fffu + ((ul >> 16) & 1u)) >> 16);
      }
      int byte = m * 128 + d0 * 2;
      int swz  = byte ^ ((m & 7) << 4);
      *(s8v*)((char*)Ah_lds + swz) = hi;
      *(s8v*)((char*)Al_lds + swz) = lo;
    }
    // dis: 8 partial dots, 3-stage reduce-scatter -> lane l8 holds kk==l8
    float msk = (float)mask[n * M_NEI + m];
    if (l8 == 0) x0v[0] = -x0v[0];            // Lorentzian sign for d=0 term
    float pk[8];
    #pragma unroll
    for (int kk = 0; kk < K_PTS; ++kk) {
      const float* xkp = xk_s + kk * D + d0;
      float pp = 0.f;
      #pragma unroll
      for (int j = 0; j < 8; ++j) pp += x0v[j] * xkp[j];
      pk[kk] = pp;
    }
    const bool hi4 = (l8 & 4);
    float s1[4];
    #pragma unroll
    for (int j = 0; j < 4; ++j) {
      float give = hi4 ? pk[j] : pk[j + 4];
      float keep = hi4 ? pk[j + 4] : pk[j];
      s1[j] = keep + swz_xor4(give);
    }
    const bool hi2 = (l8 & 2);
    float s2[2];
    #pragma unroll
    for (int j = 0; j < 2; ++j) {
      float give = hi2 ? s1[j] : s1[j + 2];
      float keep = hi2 ? s1[j + 2] : s1[j];
      s2[j] = keep + dppmov<0x4E>(give);
    }
    const bool hi1 = (l8 & 1);
    float give = hi1 ? s2[0] : s2[1];
    float keep = hi1 ? s2[1] : s2[0];
    float mypp = keep + dppmov<0xB1>(give);
    float al_ = fmaxf(-mypp, 1.f + EPS_);
    dis_s[l8 * 33 + m] = facosh(al_) * msk;
  }
  __syncthreads();

  // ---- MFMA: A-frags once (rows wm*16+cl), loop over this wave's 4 k
  const int row = wm * 16 + cl;
  s8v ah[2], alo[2];
  #pragma unroll
  for (int ks = 0; ks < 2; ++ks) {
    int byte = row * 128 + (gr * 8 + ks * 32) * 2;
    int swz  = byte ^ ((row & 7) << 4);
    ah[ks]  = *(const s8v*)((const char*)Ah_lds + swz);
    alo[ks] = *(const s8v*)((const char*)Al_lds + swz);
  }

  f4v acc[4][4];   // retained: [kq][ct]
  #pragma unroll
  for (int kq = 0; kq < 4; ++kq) {
    const int k = wk * 4 + kq;
    #pragma unroll
    for (int ct = 0; ct < 4; ++ct) {
      float bv = b[k * 64 + ct * 16 + cl];
      f4v a = (f4v){bv, bv, bv, bv};           // bias folded into C-init
      #pragma unroll
      for (int ks = 0; ks < 2; ++ks) {
        int fi = (k * 4 + ct) * 2 + ks;
        s8v bh = *(const s8v*)(WF + (size_t)(fi * 2 + 0) * 512 + l * 8);
        s8v bl = *(const s8v*)(WF + (size_t)(fi * 2 + 1) * 512 + l * 8);
        a = __builtin_amdgcn_mfma_f32_16x16x32_bf16(ah[ks],  bh, a, 0, 0, 0);
        a = __builtin_amdgcn_mfma_f32_16x16x32_bf16(ah[ks],  bl, a, 0, 0, 0);
        a = __builtin_amdgcn_mfma_f32_16x16x32_bf16(alo[ks], bh, a, 0, 0, 0);
      }
      acc[kq][ct] = a;
    }
    // pass A: ss per (k,m); cl==0 lane stores (h0, ss)
    #pragma unroll
    for (int r = 0; r < 4; ++r) {
      float ss = acc[kq][0][r]*acc[kq][0][r] + acc[kq][1][r]*acc[kq][1][r]
               + acc[kq][2][r]*acc[kq][2][r] + acc[kq][3][r]*acc[kq][3][r];
      ss = sum16(ss);
      if (cl == 0) {
        const int m = wm * 16 + gr * 4 + r;
        *(float2*)&hss[(k * M_NEI + m) * 2] = make_float2(acc[kq][0][r], ss);
      }
    }
  }
  __syncthreads();

  // ---- pass B: one (k,m) per thread — transcendental math ONCE per pair, in-place
  {
    const int k = t >> 5;
    const int m = t & 31;
    float2 hp = *(const float2*)&hss[(k * M_NEI + m) * 2];
    float h0 = hp.x, ss = hp.y;
    float nar2 = fmaxf(ss - h0 * h0, 1e-8f);
    float es   = xk[K_PTS * D + k];            // precomputed exp(scale[k])
    float time = es * frcp(1.f + __expf(-h0)) + 1.0001f;
    float sq   = fsqrt(time * time - 1.f) * frsq(nar2);
    float dm   = dis_s[k * 33 + m];
    *(float2*)&hss[(k * M_NEI + m) * 2] = make_float2(dm * sq, dm * time);
  }
  __syncthreads();

  // ---- pass C: pure FMA accumulation against broadcast (dmsq, dmtime)
  float yacc[4][4];   // [r][ct]
  #pragma unroll
  for (int r = 0; r < 4; ++r)
    #pragma unroll
    for (int ct = 0; ct < 4; ++ct) yacc[r][ct] = 0.f;

  #pragma unroll
  for (int kq = 0; kq < 4; ++kq) {
    const int k = wk * 4 + kq;
    #pragma unroll
    for (int r = 0; r < 4; ++r) {
      const int m = wm * 16 + gr * 4 + r;
      float2 dd = *(const float2*)&hss[(k * M_NEI + m) * 2];  // broadcast read
      yacc[r][0] += (cl == 0) ? dd.y : dd.x * acc[kq][0][r];
      yacc[r][1] += dd.x * acc[kq][1][r];
      yacc[r][2] += dd.x * acc[kq][2][r];
      yacc[r][3] += dd.x * acc[kq][3][r];
    }
  }

  // ---- cross-wk combine: wk=1 writes, wk=0 adds in regs and finishes
  if (wk == 1) {
    #pragma unroll
    for (int r = 0; r < 4; ++r) {
      const int ml = gr * 4 + r;
      float* rw = &red_h[wm][ml * 68];
      rw[cl]      = yacc[r][0];
      rw[16 + cl] = yacc[r][1];
      rw[32 + cl] = yacc[r][2];
      rw[48 + cl] = yacc[r][3];
    }
  }
  __syncthreads();

  if (wk == 0) {
    float s[4] = {0.f, 0.f, 0.f, 0.f};
    #pragma unroll
    for (int r = 0; r < 4; ++r) {
      const int ml = gr * 4 + r;
      const float* rw = &red_h[wm][ml * 68];
      float v0_ = yacc[r][0] + rw[cl];
      float v1_ = yacc[r][1] + rw[16 + cl];
      float v2_ = yacc[r][2] + rw[32 + cl];
      float v3_ = yacc[r][3] + rw[48 + cl];
      float ip = v0_*v0_ + v1_*v1_ + v2_*v2_ + v3_*v3_;
      if (cl == 0) ip -= 2.f * v0_ * v0_;
      ip = sum16(ip);                               // per-m l_inner
      float rin = frsq(fmaxf(fabsf(ip), 1e-8f));
      s[0] += v0_ * rin; s[1] += v1_ * rin;
      s[2] += v2_ * rin; s[3] += v3_ * rin;
    }
    // sum across gr groups (this wave's 16 m)
    #pragma unroll
    for (int j = 0; j < 4; ++j) {
      float z = s[j];
      z += __shfl_xor(z, 16); z += __shfl_xor(z, 32);
      s[j] = z;
    }
    if (gr == 0) {
      #pragma unroll
      for (int j = 0; j < 4; ++j) redp2[wm][j * 16 + cl] = s[j];
    }
  }
  __syncthreads();

  if (t < 16) {
    float mv[4]; float ip = 0.f;
    #pragma unroll
    for (int j = 0; j < 4; ++j) {
      mv[j] = (redp2[0][j * 16 + t] + redp2[1][j * 16 + t]) * (1.f / 32.f);
      ip += mv[j] * mv[j];
    }
    if (t == 0) ip -= 2.f * mv[0] * mv[0];
    ip = sum16(ip);                                 // lanes 0-15, row 0
    float rin = frsq(fmaxf(fabsf(ip), 1e-8f));
    #pragma unroll
    for (int j = 0; j < 4; ++j) out[n * D + j * 16 + t] = mv[j] * rin;
  }
}

extern "C" void kernel_launch(void* const* d_in, const int* in_sizes, int n_in,
                              void* d_out, int out_size, void* d_ws, size_t ws_size,
                              hipStream_t stream) {
  const float* x     = (const float*)d_in[0];
  const int*   nei   = (const int*)d_in[1];
  const int*   mask  = (const int*)d_in[2];
  const float* W     = (const float*)d_in[3];
  const float* b     = (const float*)d_in[4];
  const float* scale = (const float*)d_in[5];
  const float* kp    = (const float*)d_in[6];
  float* out = (float*)d_out;

  ushort* WF = (ushort*)d_ws;               // 64 frags x 2 parts x 512 ushort = 128 KiB
  float*  xk = (float*)(WF + 65536);        // 8*64 + 8 floats

  prep_wb<<<16, 256, 0, stream>>>(W, WF);
  prep_xk<<<1, 64, 0, stream>>>(kp, scale, xk);
  kpa_main<<<N_NODES, 256, 0, stream>>>(x, nei, mask, WF, b, scale, xk, out);
}

// Round 17
// 102.277 us; speedup vs baseline: 2.0423x; 1.0069x over previous
//
#include <hip/hip_runtime.h>
#include <hip/hip_bf16.h>

#define N_NODES 8192
#define M_NEI   32
#define K_PTS   8
#define D       64
#define EPS_    1e-7f

typedef float f4v __attribute__((ext_vector_type(4)));
typedef short s8v __attribute__((ext_vector_type(8)));

__device__ __forceinline__ ushort f2bf(float f) {
  __hip_bfloat16 h = __float2bfloat16(f);
  return *reinterpret_cast<ushort*>(&h);
}
__device__ __forceinline__ float bf2f(ushort u) {
  __hip_bfloat16 h;
  *reinterpret_cast<ushort*>(&h) = u;
  return __bfloat162float(h);
}
__device__ __forceinline__ float frcp(float x)  { return __builtin_amdgcn_rcpf(x); }
__device__ __forceinline__ float frsq(float x)  { return __builtin_amdgcn_rsqf(x); }
__device__ __forceinline__ float fsqrt(float x) { return __builtin_amdgcn_sqrtf(x); }
__device__ __forceinline__ float facosh(float a) {
  float den = fsqrt(fmaxf(a * a - 1.f, 1e-14f));
  return __logf(a + den);
}

// ---- DPP / swizzle cross-lane ----
template<int CTRL>
__device__ __forceinline__ float dppadd(float v) {
  int t = __builtin_amdgcn_update_dpp(0, __float_as_int(v), CTRL, 0xf, 0xf, true);
  return v + __int_as_float(t);
}
template<int CTRL>
__device__ __forceinline__ float dppmov(float v) {
  return __int_as_float(__builtin_amdgcn_update_dpp(0, __float_as_int(v), CTRL, 0xf, 0xf, true));
}
__device__ __forceinline__ float swz_xor4(float v) {   // lane ^= 4
  return __int_as_float(__builtin_amdgcn_ds_swizzle(__float_as_int(v), 0x101F));
}
__device__ __forceinline__ float sum8(float v) {
  v = dppadd<0xB1>(v);
  v = dppadd<0x4E>(v);
  v = dppadd<0x141>(v);
  return v;
}
__device__ __forceinline__ float sum16(float v) {
  v = dppadd<0x121>(v);
  v = dppadd<0x122>(v);
  v = dppadd<0x124>(v);
  v = dppadd<0x128>(v);
  return v;
}

// ---------------- prep: x_kernel rows (K x 64) + exp(scale) tail ----------------
__global__ void prep_xk(const float* __restrict__ kp, const float* __restrict__ scale,
                        float* __restrict__ xk) {
  int d = threadIdx.x;  // 64 threads
  for (int kk = 0; kk < K_PTS - 1; ++kk) {
    float v = kp[(kk + 1) * D + d];
    float p = (d == 0) ? 0.f : v * v;
    #pragma unroll
    for (int s = 1; s < 64; s <<= 1) p += __shfl_xor(p, s);
    float un = sqrtf(fmaxf(p, 1e-14f));
    float sh = sinhf(un) / un;
    xk[kk * D + d] = (d == 0) ? coshf(un) : sh * v;
  }
  xk[(K_PTS - 1) * D + d] = (d == 0) ? 1.f : 0.f;
  if (d < K_PTS) xk[K_PTS * D + d] = expf(scale[d]);
}

// ---------------- prep: W -> bf16 hi/lo MFMA B-fragments ----------------
__global__ void prep_wb(const float* __restrict__ W, ushort* __restrict__ WF) {
  int idx = blockIdx.x * 256 + threadIdx.x;   // 4096 total
  int k    = idx >> 9;
  int ct   = (idx >> 7) & 3;
  int ks   = (idx >> 6) & 1;
  int lane = idx & 63;
  int o  = ct * 16 + (lane & 15);
  int db = (lane >> 4) * 8 + ks * 32;
  const float* wrow = W + (k * 64 + o) * 64 + db;   // d-contiguous
  s8v hi, lo;
  #pragma unroll
  for (int j = 0; j < 8; ++j) {
    float w = wrow[j];
    ushort h = f2bf(w);
    hi[j] = (short)h;
    lo[j] = (short)f2bf(w - bf2f(h));
  }
  int f = (k * 4 + ct) * 2 + ks;
  *(s8v*)(WF + (size_t)(f * 2 + 0) * 512 + lane * 8) = hi;
  *(s8v*)(WF + (size_t)(f * 2 + 1) * 512 + lane * 8) = lo;
}

// ================= shared device body pieces (macro to keep both kernels in sync) =====
#define KPA_PROLOGUE_AND_DIS                                                        \
  if (t < D) xr_s[t] = x[n * D + t];                                                \
  xk_s[t] = xk[t]; xk_s[t + 256] = xk[t + 256];                                     \
  __syncthreads();                                                                  \
  {                                                                                 \
    const int m  = t >> 3;                                                          \
    const int l8 = t & 7;                                                           \
    const int d0 = l8 * 8;                                                          \
    const int ni = nei[n * M_NEI + m];                                              \
    float y[8], xr[8];                                                              \
    float y0 = x[ni * D];                                                           \
    {                                                                               \
      float4 ya = *(const float4*)(x + ni * D + d0);                                \
      float4 yb = *(const float4*)(x + ni * D + d0 + 4);                            \
      y[0]=ya.x; y[1]=ya.y; y[2]=ya.z; y[3]=ya.w;                                   \
      y[4]=yb.x; y[5]=yb.y; y[6]=yb.z; y[7]=yb.w;                                   \
      float4 ra = *(const float4*)(xr_s + d0);                                      \
      float4 rb = *(const float4*)(xr_s + d0 + 4);                                  \
      xr[0]=ra.x; xr[1]=ra.y; xr[2]=ra.z; xr[3]=ra.w;                               \
      xr[4]=rb.x; xr[5]=rb.y; xr[6]=rb.z; xr[7]=rb.w;                               \
    }                                                                               \
    const float xr0 = xr_s[0];                                                      \
    float p = 0.f;                                                                  \
    _Pragma("unroll")                                                               \
    for (int j = 0; j < 8; ++j) p += xr[j] * y[j];                                  \
    if (l8 == 0) p -= 2.f * xr[0] * y[0];                                           \
    p = sum8(p);                                                                    \
    float alpha = fmaxf(-p, 1.f + EPS_);                                            \
    float den = fsqrt(fmaxf(alpha * alpha - 1.f, 1e-14f));                          \
    float dd  = __logf(alpha + den);                                                \
    float f   = dd * frcp(den);                                                     \
    float v[8];                                                                     \
    _Pragma("unroll")                                                               \
    for (int j = 0; j < 8; ++j) v[j] = f * (y[j] - alpha * xr[j]);                  \
    float v0 = f * (y0 - alpha * xr0);                                              \
    float c  = -v0 * frcp(1.f + xr0);                                               \
    float wv[8];                                                                    \
    float q = 0.f;                                                                  \
    _Pragma("unroll")                                                               \
    for (int j = 0; j < 8; ++j) { wv[j] = v[j] + c * xr[j]; q += wv[j] * wv[j]; }   \
    if (l8 == 0) q -= wv[0] * wv[0];                                                \
    q = sum8(q);                                                                    \
    float un = fsqrt(fmaxf(q, 1e-14f));                                             \
    float e  = __expf(un);                                                          \
    float ei = frcp(e);                                                             \
    float sh = (0.5f * (e - ei)) * frcp(un);                                        \
    float x0v[8];                                                                   \
    _Pragma("unroll")                                                               \
    for (int j = 0; j < 8; ++j) x0v[j] = sh * wv[j];                                \
    if (l8 == 0) x0v[0] = 0.5f * (e + ei);                                          \
    {                                                                               \
      s8v hi, lo;                                                                   \
      _Pragma("unroll")                                                             \
      for (int j = 0; j < 8; ++j) {                                                 \
        uint u = __float_as_uint(x0v[j]);                                           \
        hi[j] = (short)(ushort)(u >> 16);                                           \
        float lof = x0v[j] - __uint_as_float(u & 0xffff0000u);                      \
        uint ul = __float_as_uint(lof);                                             \
        lo[j] = (short)(ushort)((ul + 0x7fffu + ((ul >> 16) & 1u)) >> 16);          \
      }                                                                             \
      int byte = m * 128 + d0 * 2;                                                  \
      int swz  = byte ^ ((m & 7) << 4);                                             \
      *(s8v*)((char*)Ah_lds + swz) = hi;                                            \
      *(s8v*)((char*)Al_lds + swz) = lo;                                            \
    }                                                                               \
    float msk = (float)mask[n * M_NEI + m];                                         \
    if (l8 == 0) x0v[0] = -x0v[0];                                                  \
    float pk[8];                                                                    \
    _Pragma("unroll")                                                               \
    for (int kk = 0; kk < K_PTS; ++kk) {                                            \
      const float* xkp = xk_s + kk * D + d0;                                        \
      float pp = 0.f;                                                               \
      _Pragma("unroll")                                                             \
      for (int j = 0; j < 8; ++j) pp += x0v[j] * xkp[j];                            \
      pk[kk] = pp;                                                                  \
    }                                                                               \
    const bool hi4 = (l8 & 4);                                                      \
    float s1[4];                                                                    \
    _Pragma("unroll")                                                               \
    for (int j = 0; j < 4; ++j) {                                                   \
      float give = hi4 ? pk[j] : pk[j + 4];                                         \
      float keep = hi4 ? pk[j + 4] : pk[j];                                         \
      s1[j] = keep + swz_xor4(give);                                                \
    }                                                                               \
    const bool hi2 = (l8 & 2);                                                      \
    float s2[2];                                                                    \
    _Pragma("unroll")                                                               \
    for (int j = 0; j < 2; ++j) {                                                   \
      float give = hi2 ? s1[j] : s1[j + 2];                                         \
      float keep = hi2 ? s1[j + 2] : s1[j];                                         \
      s2[j] = keep + dppmov<0x4E>(give);                                            \
    }                                                                               \
    const bool hi1 = (l8 & 1);                                                      \
    float give = hi1 ? s2[0] : s2[1];                                               \
    float keep = hi1 ? s2[1] : s2[0];                                               \
    float mypp = keep + dppmov<0xB1>(give);                                         \
    float al_ = fmaxf(-mypp, 1.f + EPS_);                                           \
    dis_s[l8 * 33 + m] = facosh(al_) * msk;                                         \
  }                                                                                 \
  __syncthreads();

#define KPA_EPILOGUE                                                                \
  if (wk == 1) {                                                                    \
    _Pragma("unroll")                                                               \
    for (int r = 0; r < 4; ++r) {                                                   \
      const int ml = gr * 4 + r;                                                    \
      float* rw = &red_h[wm][ml * 68];                                              \
      rw[cl]      = yacc[r][0];                                                     \
      rw[16 + cl] = yacc[r][1];                                                     \
      rw[32 + cl] = yacc[r][2];                                                     \
      rw[48 + cl] = yacc[r][3];                                                     \
    }                                                                               \
  }                                                                                 \
  __syncthreads();                                                                  \
  if (wk == 0) {                                                                    \
    float s[4] = {0.f, 0.f, 0.f, 0.f};                                              \
    _Pragma("unroll")                                                               \
    for (int r = 0; r < 4; ++r) {                                                   \
      const int ml = gr * 4 + r;                                                    \
      const float* rw = &red_h[wm][ml * 68];                                        \
      float v0_ = yacc[r][0] + rw[cl];                                              \
      float v1_ = yacc[r][1] + rw[16 + cl];                                         \
      float v2_ = yacc[r][2] + rw[32 + cl];                                         \
      float v3_ = yacc[r][3] + rw[48 + cl];                                         \
      float ip = v0_*v0_ + v1_*v1_ + v2_*v2_ + v3_*v3_;                             \
      if (cl == 0) ip -= 2.f * v0_ * v0_;                                           \
      ip = sum16(ip);                                                               \
      float rin = frsq(fmaxf(fabsf(ip), 1e-8f));                                    \
      s[0] += v0_ * rin; s[1] += v1_ * rin;                                         \
      s[2] += v2_ * rin; s[3] += v3_ * rin;                                         \
    }                                                                               \
    _Pragma("unroll")                                                               \
    for (int j = 0; j < 4; ++j) {                                                   \
      float z = s[j];                                                               \
      z += __shfl_xor(z, 16); z += __shfl_xor(z, 32);                               \
      s[j] = z;                                                                     \
    }                                                                               \
    if (gr == 0) {                                                                  \
      _Pragma("unroll")                                                             \
      for (int j = 0; j < 4; ++j) redp2[wm][j * 16 + cl] = s[j];                    \
    }                                                                               \
  }                                                                                 \
  __syncthreads();                                                                  \
  if (t < 16) {                                                                     \
    float mv[4]; float ip = 0.f;                                                    \
    _Pragma("unroll")                                                               \
    for (int j = 0; j < 4; ++j) {                                                   \
      mv[j] = (redp2[0][j * 16 + t] + redp2[1][j * 16 + t]) * (1.f / 32.f);         \
      ip += mv[j] * mv[j];                                                          \
    }                                                                               \
    if (t == 0) ip -= 2.f * mv[0] * mv[0];                                          \
    ip = sum16(ip);                                                                 \
    float rin = frsq(fmaxf(fabsf(ip), 1e-8f));                                      \
    _Pragma("unroll")                                                               \
    for (int j = 0; j < 4; ++j) out[n * D + j * 16 + t] = mv[j] * rin;              \
  }

// ---- kpa_main4: proven r16 config — (256,4), acc[4][4] retained, 3-pass dedup ----
__launch_bounds__(256, 4)
__global__ void kpa_main4(const float* __restrict__ x, const int* __restrict__ nei,
                          const int* __restrict__ mask, const ushort* __restrict__ WF,
                          const float* __restrict__ b, const float* __restrict__ scale,
                          const float* __restrict__ xk, float* __restrict__ out) {
  __shared__ __align__(16) float  xr_s[D];
  __shared__ __align__(16) float  xk_s[K_PTS * D];
  __shared__ __align__(16) ushort Ah_lds[M_NEI * D];
  __shared__ __align__(16) ushort Al_lds[M_NEI * D];
  __shared__ float dis_s[K_PTS * 33];
  __shared__ __align__(8)  float  hss[K_PTS * M_NEI * 2];
  __shared__ __align__(16) float  red_h[2][16 * 68];
  __shared__ __align__(16) float  redp2[2][64];

  const int n  = blockIdx.x;
  const int t  = threadIdx.x;
  const int w4 = t >> 6;
  const int l  = t & 63;
  const int cl = l & 15;
  const int gr = l >> 4;
  const int wm = w4 & 1;
  const int wk = w4 >> 1;

  KPA_PROLOGUE_AND_DIS

  const int row = wm * 16 + cl;
  s8v ah[2], alo[2];
  #pragma unroll
  for (int ks = 0; ks < 2; ++ks) {
    int byte = row * 128 + (gr * 8 + ks * 32) * 2;
    int swz  = byte ^ ((row & 7) << 4);
    ah[ks]  = *(const s8v*)((const char*)Ah_lds + swz);
    alo[ks] = *(const s8v*)((const char*)Al_lds + swz);
  }

  f4v acc[4][4];
  #pragma unroll
  for (int kq = 0; kq < 4; ++kq) {
    const int k = wk * 4 + kq;
    #pragma unroll
    for (int ct = 0; ct < 4; ++ct) {
      float bv = b[k * 64 + ct * 16 + cl];
      f4v a = (f4v){bv, bv, bv, bv};
      #pragma unroll
      for (int ks = 0; ks < 2; ++ks) {
        int fi = (k * 4 + ct) * 2 + ks;
        s8v bh = *(const s8v*)(WF + (size_t)(fi * 2 + 0) * 512 + l * 8);
        s8v bl = *(const s8v*)(WF + (size_t)(fi * 2 + 1) * 512 + l * 8);
        a = __builtin_amdgcn_mfma_f32_16x16x32_bf16(ah[ks],  bh, a, 0, 0, 0);
        a = __builtin_amdgcn_mfma_f32_16x16x32_bf16(ah[ks],  bl, a, 0, 0, 0);
        a = __builtin_amdgcn_mfma_f32_16x16x32_bf16(alo[ks], bh, a, 0, 0, 0);
      }
      acc[kq][ct] = a;
    }
    #pragma unroll
    for (int r = 0; r < 4; ++r) {
      float ss = acc[kq][0][r]*acc[kq][0][r] + acc[kq][1][r]*acc[kq][1][r]
               + acc[kq][2][r]*acc[kq][2][r] + acc[kq][3][r]*acc[kq][3][r];
      ss = sum16(ss);
      if (cl == 0) {
        const int m = wm * 16 + gr * 4 + r;
        *(float2*)&hss[(k * M_NEI + m) * 2] = make_float2(acc[kq][0][r], ss);
      }
    }
  }
  __syncthreads();

  {
    const int k = t >> 5;
    const int m = t & 31;
    float2 hp = *(const float2*)&hss[(k * M_NEI + m) * 2];
    float h0 = hp.x, ss = hp.y;
    float nar2 = fmaxf(ss - h0 * h0, 1e-8f);
    float es   = xk[K_PTS * D + k];
    float time = es * frcp(1.f + __expf(-h0)) + 1.0001f;
    float sq   = fsqrt(time * time - 1.f) * frsq(nar2);
    float dm   = dis_s[k * 33 + m];
    *(float2*)&hss[(k * M_NEI + m) * 2] = make_float2(dm * sq, dm * time);
  }
  __syncthreads();

  float yacc[4][4];
  #pragma unroll
  for (int r = 0; r < 4; ++r)
    #pragma unroll
    for (int ct = 0; ct < 4; ++ct) yacc[r][ct] = 0.f;

  #pragma unroll
  for (int kq = 0; kq < 4; ++kq) {
    const int k = wk * 4 + kq;
    #pragma unroll
    for (int r = 0; r < 4; ++r) {
      const int m = wm * 16 + gr * 4 + r;
      float2 dd = *(const float2*)&hss[(k * M_NEI + m) * 2];
      yacc[r][0] += (cl == 0) ? dd.y : dd.x * acc[kq][0][r];
      yacc[r][1] += dd.x * acc[kq][1][r];
      yacc[r][2] += dd.x * acc[kq][2][r];
      yacc[r][3] += dd.x * acc[kq][3][r];
    }
  }

  KPA_EPILOGUE
}

// ---- kpa_main5: per-kq fold + unroll 1 (blocks load-batching) at (256,5) ----
// Mechanism bet: r13-r15 spills came from full-unroll hoisting up to 64 B-frag
// loads; unroll 1 caps in-flight loads at 16 -> live set ~80 regs fits 102 cap.
// Host falls back to kpa_main4 if this kernel reports localSizeBytes != 0.
__launch_bounds__(256, 5)
__global__ void kpa_main5(const float* __restrict__ x, const int* __restrict__ nei,
                          const int* __restrict__ mask, const ushort* __restrict__ WF,
                          const float* __restrict__ b, const float* __restrict__ scale,
                          const float* __restrict__ xk, float* __restrict__ out) {
  __shared__ __align__(16) float  xr_s[D];
  __shared__ __align__(16) float  xk_s[K_PTS * D];
  __shared__ __align__(16) ushort Ah_lds[M_NEI * D];
  __shared__ __align__(16) ushort Al_lds[M_NEI * D];
  __shared__ float dis_s[K_PTS * 33];
  __shared__ __align__(8)  float  hss[K_PTS * M_NEI * 2];
  __shared__ __align__(16) float  red_h[2][16 * 68];
  __shared__ __align__(16) float  redp2[2][64];

  const int n  = blockIdx.x;
  const int t  = threadIdx.x;
  const int w4 = t >> 6;
  const int l  = t & 63;
  const int cl = l & 15;
  const int gr = l >> 4;
  const int wm = w4 & 1;
  const int wk = w4 >> 1;

  KPA_PROLOGUE_AND_DIS

  const int row = wm * 16 + cl;
  s8v ah[2], alo[2];
  #pragma unroll
  for (int ks = 0; ks < 2; ++ks) {
    int byte = row * 128 + (gr * 8 + ks * 32) * 2;
    int swz  = byte ^ ((row & 7) << 4);
    ah[ks]  = *(const s8v*)((const char*)Ah_lds + swz);
    alo[ks] = *(const s8v*)((const char*)Al_lds + swz);
  }

  float yacc[4][4];
  #pragma unroll
  for (int r = 0; r < 4; ++r)
    #pragma unroll
    for (int ct = 0; ct < 4; ++ct) yacc[r][ct] = 0.f;

  #pragma unroll 1
  for (int kq = 0; kq < 4; ++kq) {
    const int k = wk * 4 + kq;
    f4v acc[4];   // one kq retained -> 16 regs; dies each iteration
    #pragma unroll
    for (int ct = 0; ct < 4; ++ct) {
      float bv = b[k * 64 + ct * 16 + cl];
      f4v a = (f4v){bv, bv, bv, bv};
      #pragma unroll
      for (int ks = 0; ks < 2; ++ks) {
        int fi = (k * 4 + ct) * 2 + ks;
        s8v bh = *(const s8v*)(WF + (size_t)(fi * 2 + 0) * 512 + l * 8);
        s8v bl = *(const s8v*)(WF + (size_t)(fi * 2 + 1) * 512 + l * 8);
        a = __builtin_amdgcn_mfma_f32_16x16x32_bf16(ah[ks],  bh, a, 0, 0, 0);
        a = __builtin_amdgcn_mfma_f32_16x16x32_bf16(ah[ks],  bl, a, 0, 0, 0);
        a = __builtin_amdgcn_mfma_f32_16x16x32_bf16(alo[ks], bh, a, 0, 0, 0);
      }
      acc[ct] = a;
    }
    // pass A: ss per (k,m); cl==0 lane stores (h0, ss)  [wave-local pairs]
    #pragma unroll
    for (int r = 0; r < 4; ++r) {
      float ss = acc[0][r]*acc[0][r] + acc[1][r]*acc[1][r]
               + acc[2][r]*acc[2][r] + acc[3][r]*acc[3][r];
      ss = sum16(ss);
      if (cl == 0) {
        const int m = wm * 16 + gr * 4 + r;
        *(float2*)&hss[(k * M_NEI + m) * 2] = make_float2(acc[0][r], ss);
      }
    }
    // mini pass B: wave-local (wave owns its (k,m) region; no barrier needed)
    {
      const float es = xk[K_PTS * D + k];   // wave-uniform s_load
      if (l < 16) {
        const int mB = wm * 16 + l;
        float2 hp = *(const float2*)&hss[(k * M_NEI + mB) * 2];
        float h0 = hp.x, ss = hp.y;
        float nar2 = fmaxf(ss - h0 * h0, 1e-8f);
        float time = es * frcp(1.f + __expf(-h0)) + 1.0001f;
        float sq   = fsqrt(time * time - 1.f) * frsq(nar2);
        float dm   = dis_s[k * 33 + mB];
        *(float2*)&hss[(k * M_NEI + mB) * 2] = make_float2(dm * sq, dm * time);
      }
    }
    // pass C: FMA accumulation against broadcast (dmsq, dmtime)
    #pragma unroll
    for (int r = 0; r < 4; ++r) {
      const int m = wm * 16 + gr * 4 + r;
      float2 dd = *(const float2*)&hss[(k * M_NEI + m) * 2];
      yacc[r][0] += (cl == 0) ? dd.y : dd.x * acc[0][r];
      yacc[r][1] += dd.x * acc[1][r];
      yacc[r][2] += dd.x * acc[2][r];
      yacc[r][3] += dd.x * acc[3][r];
    }
  }

  KPA_EPILOGUE
}

extern "C" void kernel_launch(void* const* d_in, const int* in_sizes, int n_in,
                              void* d_out, int out_size, void* d_ws, size_t ws_size,
                              hipStream_t stream) {
  const float* x     = (const float*)d_in[0];
  const int*   nei   = (const int*)d_in[1];
  const int*   mask  = (const int*)d_in[2];
  const float* W     = (const float*)d_in[3];
  const float* b     = (const float*)d_in[4];
  const float* scale = (const float*)d_in[5];
  const float* kp    = (const float*)d_in[6];
  float* out = (float*)d_out;

  ushort* WF = (ushort*)d_ws;               // 64 frags x 2 parts x 512 ushort = 128 KiB
  float*  xk = (float*)(WF + 65536);        // 8*64 + 8 floats

  prep_wb<<<16, 256, 0, stream>>>(W, WF);
  prep_xk<<<1, 64, 0, stream>>>(kp, scale, xk);

  // Spill-detecting dispatch: use the 5-wave kernel only if it allocated
  // with zero scratch (localSizeBytes == 0). Deterministic; not a stream op.
  hipFuncAttributes a5;
  bool use5 = (hipFuncGetAttributes(&a5, (const void*)kpa_main5) == hipSuccess)
              && (a5.localSizeBytes == 0);
  if (use5)
    kpa_main5<<<N_NODES, 256, 0, stream>>>(x, nei, mask, WF, b, scale, xk, out);
  else
    kpa_main4<<<N_NODES, 256, 0, stream>>>(x, nei, mask, WF, b, scale, xk, out);
}